// Round 1
// baseline (5567.845 us; speedup 1.0000x reference)
//
#include <hip/hip_runtime.h>
#include <cstdint>
#include <cstddef>

// Problem constants (fixed by setup_inputs)
#define BB    16
#define NTOK  4096
#define DIMC  512
#define INNER 512
#define CTXC  256
#define HDIM  64
#define WDIM  64
#define HEADS 8
#define HD    64
#define AG    49

// ---------------- workspace layout (floats) ----------------
static const size_t Q_OFF   = 0;                                     // q / out_pre: 16*4096*512
static const size_t KV_OFF  = Q_OFF  + (size_t)BB*NTOK*INNER;        // kv: 16*4096*1024
static const size_t A2_OFF  = KV_OFF + (size_t)BB*NTOK*2*INNER;      // pooled concat: 16*49*768
static const size_t COL_OFF = A2_OFF + (size_t)BB*AG*768;            // im2col: 784*6912
static const size_t CG_OFF  = COL_OFF+ (size_t)BB*AG*768*9;          // conv gemm out: 784*512
static const size_t AGT_OFF = CG_OFF + (size_t)BB*AG*INNER;          // agent[b,h,a,d]
static const size_t AGV_OFF = AGT_OFF+ (size_t)BB*HEADS*AG*HD;       // agent_v[b,h,a,d]
static const size_t PB_OFF  = AGV_OFF+ (size_t)BB*HEADS*AG*HD;       // pb[h,a,n]
static const size_t AB_OFF  = PB_OFF + (size_t)HEADS*AG*NTOK;        // ab[h,n,a]
// total = 111,099,904 floats = 444.4 MB

// ---------------- GEMM 128x128 tile, C = A(MxK) * Bw(NxK)^T (+bias) ----------------
template <bool ADD_BIAS>
__global__ __launch_bounds__(256) void gemm128(const float* __restrict__ A,
                                               const float* __restrict__ Bw,
                                               const float* __restrict__ bias,
                                               float* __restrict__ C,
                                               int M, int Nc, int K) {
  __shared__ float As[16][128];
  __shared__ float Bs[16][128];
  const int tid = threadIdx.x;
  const int tx = tid & 15, ty = tid >> 4;
  const int bm = blockIdx.y * 128;
  const int bn = blockIdx.x * 128;
  float acc[8][8] = {};
  for (int k0 = 0; k0 < K; k0 += 16) {
#pragma unroll
    for (int l = 0; l < 2; ++l) {
      int f = tid + l * 256;            // 0..511
      int row = f >> 2;                 // 0..127
      int c4 = (f & 3) << 2;            // 0,4,8,12
      float4 av = *(const float4*)(A + (size_t)(bm + row) * K + k0 + c4);
      As[c4 + 0][row] = av.x; As[c4 + 1][row] = av.y;
      As[c4 + 2][row] = av.z; As[c4 + 3][row] = av.w;
      float4 bv = *(const float4*)(Bw + (size_t)(bn + row) * K + k0 + c4);
      Bs[c4 + 0][row] = bv.x; Bs[c4 + 1][row] = bv.y;
      Bs[c4 + 2][row] = bv.z; Bs[c4 + 3][row] = bv.w;
    }
    __syncthreads();
#pragma unroll
    for (int k = 0; k < 16; ++k) {
      float a[8], b[8];
#pragma unroll
      for (int i = 0; i < 8; ++i) a[i] = As[k][ty * 8 + i];
#pragma unroll
      for (int j = 0; j < 8; ++j) b[j] = Bs[k][tx * 8 + j];
#pragma unroll
      for (int i = 0; i < 8; ++i)
#pragma unroll
        for (int j = 0; j < 8; ++j) acc[i][j] = fmaf(a[i], b[j], acc[i][j]);
    }
    __syncthreads();
  }
#pragma unroll
  for (int i = 0; i < 8; ++i) {
    size_t m = (size_t)bm + ty * 8 + i;
    float o[8];
#pragma unroll
    for (int j = 0; j < 8; ++j) {
      o[j] = acc[i][j];
      if (ADD_BIAS) o[j] += bias[bn + tx * 8 + j];
    }
    float4 v0 = {o[0], o[1], o[2], o[3]};
    float4 v1 = {o[4], o[5], o[6], o[7]};
    *(float4*)(C + m * Nc + bn + tx * 8 + 0) = v0;
    *(float4*)(C + m * Nc + bn + tx * 8 + 4) = v1;
  }
}

// ---------------- GEMM 64x64 tile with bounds (for conv im2col GEMM) ----------------
__global__ __launch_bounds__(256) void gemm64(const float* __restrict__ A,
                                              const float* __restrict__ Bw,
                                              float* __restrict__ C,
                                              int M, int Nc, int K) {
  __shared__ float As[16][64];
  __shared__ float Bs[16][64];
  const int tid = threadIdx.x;
  const int tx = tid & 15, ty = tid >> 4;
  const int bm = blockIdx.y * 64;
  const int bn = blockIdx.x * 64;
  float acc[4][4] = {};
  for (int k0 = 0; k0 < K; k0 += 16) {
#pragma unroll
    for (int l = 0; l < 4; ++l) {
      int f = tid + l * 256;           // 0..1023
      int row = f >> 4, col = f & 15;
      As[col][row] = (bm + row < M) ? A[(size_t)(bm + row) * K + k0 + col] : 0.f;
      Bs[col][row] = (bn + row < Nc) ? Bw[(size_t)(bn + row) * K + k0 + col] : 0.f;
    }
    __syncthreads();
#pragma unroll
    for (int k = 0; k < 16; ++k) {
      float a[4], b[4];
#pragma unroll
      for (int i = 0; i < 4; ++i) a[i] = As[k][ty * 4 + i];
#pragma unroll
      for (int j = 0; j < 4; ++j) b[j] = Bs[k][tx * 4 + j];
#pragma unroll
      for (int i = 0; i < 4; ++i)
#pragma unroll
        for (int j = 0; j < 4; ++j) acc[i][j] = fmaf(a[i], b[j], acc[i][j]);
    }
    __syncthreads();
  }
#pragma unroll
  for (int i = 0; i < 4; ++i) {
    int m = bm + ty * 4 + i;
    if (m >= M) continue;
#pragma unroll
    for (int j = 0; j < 4; ++j) {
      int n = bn + tx * 4 + j;
      if (n < Nc) C[(size_t)m * Nc + n] = acc[i][j];
    }
  }
}

// ---------------- overlapping avg-pool of q and context -> A2[b,49,768] ----------------
__global__ void pool_kernel(const float* __restrict__ q, const float* __restrict__ ctx,
                            float* __restrict__ A2) {
  const int p = blockIdx.x;   // 0..48
  const int b = blockIdx.y;
  const int i = p / 7, j = p % 7;
  const int hs = i * 64 / 7, he = ((i + 1) * 64 + 6) / 7;
  const int ws = j * 64 / 7, we = ((j + 1) * 64 + 6) / 7;
  const float inv = 1.f / (float)((he - hs) * (we - ws));
  for (int ch = threadIdx.x; ch < 768; ch += 256) {
    float s = 0.f;
    if (ch < 512) {
      for (int h = hs; h < he; ++h)
        for (int w = ws; w < we; ++w)
          s += q[((size_t)(b * NTOK) + h * 64 + w) * INNER + ch];
    } else {
      int cc = ch - 512;
      for (int h = hs; h < he; ++h)
        for (int w = ws; w < we; ++w)
          s += ctx[((size_t)(b * NTOK) + h * 64 + w) * CTXC + cc];
    }
    A2[((size_t)b * AG + p) * 768 + ch] = s * inv;
  }
}

// ---------------- im2col of scrambled agent_in: Col[b*49+p][ic*9+ky*3+kx] ----------------
__global__ void im2col_kernel(const float* __restrict__ A2, float* __restrict__ Col) {
  int idx = blockIdx.x * 256 + threadIdx.x;    // 784*6912
  if (idx >= 784 * 6912) return;
  int r = idx / 6912, t = idx % 6912;
  int ic = t / 9, ky = (t % 9) / 3, kx = t % 3;
  int b = r / AG, p = r % AG;
  int y = p / 7 + ky - 1, x = p % 7 + kx - 1;
  float v = 0.f;
  if (y >= 0 && y < 7 && x >= 0 && x < 7) {
    int g = ic * 49 + y * 7 + x;              // agent_in[b][ic][y][x] = A2[b][g/768][g%768]
    v = A2[((size_t)b * AG + g / 768) * 768 + (g % 768)];
  }
  Col[(size_t)idx] = v;
}

// ---------------- scramble conv output -> agent[b,h,a,d] (+conv bias) ----------------
__global__ void agent_scatter_kernel(const float* __restrict__ Cg, const float* __restrict__ conv_b,
                                     float* __restrict__ agent) {
  int idx = blockIdx.x * 256 + threadIdx.x;   // 16*8*49*64
  if (idx >= BB * HEADS * AG * HD) return;
  int d = idx & 63;
  int a = (idx >> 6) % AG;
  int h = (idx / (64 * AG)) % HEADS;
  int b = idx / (64 * AG * HEADS);
  int f = a * 512 + h * 64 + d;               // reshape (b,512,49)->(b,49,8,64)
  int oc = f / 49, p = f % 49;
  agent[idx] = Cg[((size_t)b * AG + p) * INNER + oc] + conv_b[oc];
}

// ---------------- jax bilinear resize 7->64 (half-pixel, renorm == clamp) ----------------
__device__ inline float bilinear7(const float* __restrict__ Bm, int y, int x) {
  float fy = (y + 0.5f) * (7.f / 64.f) - 0.5f;
  float fx = (x + 0.5f) * (7.f / 64.f) - 0.5f;
  fy = fminf(fmaxf(fy, 0.f), 6.f);
  fx = fminf(fmaxf(fx, 0.f), 6.f);
  int y0 = min((int)floorf(fy), 5);
  int x0 = min((int)floorf(fx), 5);
  float ty = fy - y0, tx = fx - x0;
  float v00 = Bm[y0 * 7 + x0],     v01 = Bm[y0 * 7 + x0 + 1];
  float v10 = Bm[(y0 + 1) * 7 + x0], v11 = Bm[(y0 + 1) * 7 + x0 + 1];
  return (1.f - ty) * ((1.f - tx) * v00 + tx * v01) + ty * ((1.f - tx) * v10 + tx * v11);
}

// pb[h][a][n] = resize(an_bias[h,a])(y,x) + ah[h,a,y] + aw[h,a,x]
__global__ void pb_kernel(const float* __restrict__ an_bias, const float* __restrict__ ah,
                          const float* __restrict__ aw, float* __restrict__ pb) {
  int idx = blockIdx.x * 256 + threadIdx.x;   // 8*49*4096
  if (idx >= HEADS * AG * NTOK) return;
  int nn = idx & (NTOK - 1);
  int a = (idx / NTOK) % AG;
  int h = idx / (NTOK * AG);
  int y = nn >> 6, x = nn & 63;
  float v = bilinear7(an_bias + ((size_t)h * AG + a) * 49, y, x);
  v += ah[((size_t)h * AG + a) * 64 + y] + aw[((size_t)h * AG + a) * 64 + x];
  pb[idx] = v;
}

// ab[h][n][a] = resize(na_bias[h,a])(y,x) + ha[h,y,a] + wa[h,x,a]
__global__ void ab_kernel(const float* __restrict__ na_bias, const float* __restrict__ ha,
                          const float* __restrict__ wa, float* __restrict__ ab) {
  int idx = blockIdx.x * 256 + threadIdx.x;   // 8*4096*49
  if (idx >= HEADS * NTOK * AG) return;
  int a = idx % AG;
  int nn = (idx / AG) & (NTOK - 1);
  int h = idx / (AG * NTOK);
  int y = nn >> 6, x = nn & 63;
  float v = bilinear7(na_bias + ((size_t)h * AG + a) * 49, y, x);
  v += ha[((size_t)h * 64 + y) * AG + a] + wa[((size_t)h * 64 + x) * AG + a];
  ab[idx] = v;
}

// ---------------- agent attention: softmax_n(agent*scale . k^T + pb) @ v ----------------
__global__ __launch_bounds__(256) void agent_attn_kernel(const float* __restrict__ kv,
                                                         const float* __restrict__ agent,
                                                         const float* __restrict__ pb,
                                                         float* __restrict__ agent_v) {
  const int a = blockIdx.x, h = blockIdx.y, b = blockIdx.z;
  __shared__ float sc[NTOK];
  __shared__ float agv[64];
  __shared__ float red[256];
  const int tid = threadIdx.x;
  if (tid < 64) agv[tid] = agent[(((size_t)(b * HEADS + h)) * AG + a) * HD + tid] * 0.125f;
  __syncthreads();
  const float* kbase = kv + (size_t)b * NTOK * 1024 + h * 64;
  const float* pbb = pb + ((size_t)h * AG + a) * NTOK;
  float lmax = -3.4e38f;
  for (int nn = tid; nn < NTOK; nn += 256) {
    const float* kr = kbase + (size_t)nn * 1024;
    float dot = 0.f;
#pragma unroll
    for (int d = 0; d < 64; d += 4) {
      float4 kk = *(const float4*)(kr + d);
      dot += agv[d] * kk.x + agv[d + 1] * kk.y + agv[d + 2] * kk.z + agv[d + 3] * kk.w;
    }
    float s = dot + pbb[nn];
    sc[nn] = s;
    lmax = fmaxf(lmax, s);
  }
  red[tid] = lmax; __syncthreads();
  for (int s2 = 128; s2 > 0; s2 >>= 1) {
    if (tid < s2) red[tid] = fmaxf(red[tid], red[tid + s2]);
    __syncthreads();
  }
  const float M = red[0];
  __syncthreads();
  float lsum = 0.f;
  for (int nn = tid; nn < NTOK; nn += 256) {
    float e = __expf(sc[nn] - M);
    sc[nn] = e;
    lsum += e;
  }
  red[tid] = lsum; __syncthreads();
  for (int s2 = 128; s2 > 0; s2 >>= 1) {
    if (tid < s2) red[tid] += red[tid + s2];
    __syncthreads();
  }
  const float invL = 1.f / red[0];
  __syncthreads();
  // out[d] = sum_n sc[n]*v[n][d]
  const int d = tid & 63, chunk = tid >> 6;   // 4 chunks of 1024
  const float* vbase = kv + (size_t)b * NTOK * 1024 + 512 + h * 64 + d;
  float acc = 0.f;
#pragma unroll 4
  for (int nn = chunk * 1024; nn < (chunk + 1) * 1024; ++nn)
    acc = fmaf(sc[nn], vbase[(size_t)nn * 1024], acc);
  red[tid] = acc; __syncthreads();
  if (tid < 64) {
    float r = red[tid] + red[tid + 64] + red[tid + 128] + red[tid + 192];
    agent_v[(((size_t)(b * HEADS + h)) * AG + a) * HD + tid] = r * invL;
  }
}

// ---------------- q attention fused: softmax_a(q*scale . agent^T + ab) @ agent_v ----------------
// overwrites q buffer in place with out_pre[b,n,h*64+d]
__global__ __launch_bounds__(256) void q_attn_kernel(const float* __restrict__ agent,
                                                     const float* __restrict__ agent_v,
                                                     const float* __restrict__ ab,
                                                     float* __restrict__ q) {
  const int tile = blockIdx.x;   // 16 tiles of 256 tokens
  const int h = blockIdx.y, b = blockIdx.z;
  __shared__ float ag[AG][HD];
  __shared__ float av[AG][HD];
  const int tid = threadIdx.x;
  const size_t base = ((size_t)(b * HEADS + h)) * AG * HD;
  for (int t = tid; t < AG * HD; t += 256) {
    ag[t / HD][t % HD] = agent[base + t] * 0.125f;
    av[t / HD][t % HD] = agent_v[base + t];
  }
  __syncthreads();
  const int nn = tile * 256 + tid;
  float* qrow = q + ((size_t)(b * NTOK) + nn) * INNER + h * 64;
  float qr[64];
#pragma unroll
  for (int d = 0; d < 64; d += 4) {
    float4 v4 = *(const float4*)(qrow + d);
    qr[d] = v4.x; qr[d + 1] = v4.y; qr[d + 2] = v4.z; qr[d + 3] = v4.w;
  }
  const float* abr = ab + ((size_t)h * NTOK + nn) * AG;
  float scr[AG];
  float m = -3.4e38f;
  for (int a = 0; a < AG; ++a) {
    float dot = 0.f;
#pragma unroll
    for (int d = 0; d < 64; ++d) dot = fmaf(qr[d], ag[a][d], dot);
    float s = dot + abr[a];
    scr[a] = s;
    m = fmaxf(m, s);
  }
  float l = 0.f;
  for (int a = 0; a < AG; ++a) {
    float e = __expf(scr[a] - m);
    scr[a] = e;
    l += e;
  }
  const float invl = 1.f / l;
#pragma unroll
  for (int d = 0; d < 64; ++d) qr[d] = 0.f;
  for (int a = 0; a < AG; ++a) {
    float p = scr[a] * invl;
#pragma unroll
    for (int d = 0; d < 64; ++d) qr[d] = fmaf(p, av[a][d], qr[d]);
  }
#pragma unroll
  for (int d = 0; d < 64; d += 4) {
    float4 v4 = {qr[d], qr[d + 1], qr[d + 2], qr[d + 3]};
    *(float4*)(qrow + d) = v4;
  }
}

// ---------------- depthwise 3x3 conv on v, added into out_pre ----------------
__global__ void dwc_kernel(const float* __restrict__ kv, const float* __restrict__ dwc_w,
                           const float* __restrict__ dwc_b, float* __restrict__ outp) {
  size_t idx = (size_t)blockIdx.x * 256 + threadIdx.x;   // 16*4096*512
  int c = (int)(idx & 511);
  size_t r = idx >> 9;
  int x = (int)(r & 63);
  int y = (int)((r >> 6) & 63);
  int b = (int)(r >> 12);
  const float* vb = kv + (size_t)b * NTOK * 1024 + 512 + c;
  float s = dwc_b[c];
#pragma unroll
  for (int ky = 0; ky < 3; ++ky) {
    int yy = y + ky - 1;
    if (yy < 0 || yy > 63) continue;
#pragma unroll
    for (int kx = 0; kx < 3; ++kx) {
      int xx = x + kx - 1;
      if (xx < 0 || xx > 63) continue;
      s = fmaf(dwc_w[c * 9 + ky * 3 + kx], vb[(size_t)(yy * 64 + xx) * 1024], s);
    }
  }
  outp[idx] += s;
}

// ---------------- host launcher ----------------
extern "C" void kernel_launch(void* const* d_in, const int* in_sizes, int n_in,
                              void* d_out, int out_size, void* d_ws, size_t ws_size,
                              hipStream_t stream) {
  const float* x       = (const float*)d_in[0];
  const float* context = (const float*)d_in[1];
  const float* q_w     = (const float*)d_in[2];
  const float* kv_w    = (const float*)d_in[3];
  const float* proj_w  = (const float*)d_in[4];
  const float* proj_b  = (const float*)d_in[5];
  const float* conv_w  = (const float*)d_in[6];
  const float* conv_b  = (const float*)d_in[7];
  const float* dwc_w   = (const float*)d_in[8];
  const float* dwc_b   = (const float*)d_in[9];
  const float* an_bias = (const float*)d_in[10];
  const float* na_bias = (const float*)d_in[11];
  const float* ah_bias = (const float*)d_in[12];
  const float* aw_bias = (const float*)d_in[13];
  const float* ha_bias = (const float*)d_in[14];
  const float* wa_bias = (const float*)d_in[15];
  float* out = (float*)d_out;
  float* wsf = (float*)d_ws;

  float* q_buf  = wsf + Q_OFF;    // later becomes out_pre
  float* kv_buf = wsf + KV_OFF;
  float* A2     = wsf + A2_OFF;
  float* Col    = wsf + COL_OFF;
  float* Cg     = wsf + CG_OFF;
  float* agent  = wsf + AGT_OFF;
  float* agentv = wsf + AGV_OFF;
  float* pb     = wsf + PB_OFF;
  float* ab     = wsf + AB_OFF;

  const int M = BB * NTOK;   // 65536

  // 1. q = x @ q_w^T
  gemm128<false><<<dim3(INNER / 128, M / 128), 256, 0, stream>>>(x, q_w, nullptr, q_buf, M, INNER, DIMC);
  // 2. kv = x @ kv_w^T
  gemm128<false><<<dim3(2 * INNER / 128, M / 128), 256, 0, stream>>>(x, kv_w, nullptr, kv_buf, M, 2 * INNER, DIMC);
  // 3. pooled concat
  pool_kernel<<<dim3(AG, BB), 256, 0, stream>>>(q_buf, context, A2);
  // 4. im2col
  im2col_kernel<<<(784 * 6912 + 255) / 256, 256, 0, stream>>>(A2, Col);
  // 5. conv as GEMM: Cg[784][512] = Col[784][6912] @ conv_w[512][6912]^T
  gemm64<<<dim3((INNER + 63) / 64, (784 + 63) / 64), 256, 0, stream>>>(Col, conv_w, Cg, 784, INNER, 6912);
  // 6. scramble + conv bias -> agent[b,h,a,d]
  agent_scatter_kernel<<<(BB * HEADS * AG * HD + 255) / 256, 256, 0, stream>>>(Cg, conv_b, agent);
  // 7./8. bias tables
  pb_kernel<<<(HEADS * AG * NTOK + 255) / 256, 256, 0, stream>>>(an_bias, ah_bias, aw_bias, pb);
  ab_kernel<<<(HEADS * NTOK * AG + 255) / 256, 256, 0, stream>>>(na_bias, ha_bias, wa_bias, ab);
  // 9. agent attention -> agent_v
  agent_attn_kernel<<<dim3(AG, HEADS, BB), 256, 0, stream>>>(kv_buf, agent, pb, agentv);
  // 10. q attention (q_buf overwritten with out_pre)
  q_attn_kernel<<<dim3(NTOK / 256, HEADS, BB), 256, 0, stream>>>(agent, agentv, ab, q_buf);
  // 11. depthwise conv on v added into out_pre
  dwc_kernel<<<(BB * NTOK * INNER) / 256, 256, 0, stream>>>(kv_buf, dwc_w, dwc_b, q_buf);
  // 12. final projection with bias
  gemm128<true><<<dim3(DIMC / 128, M / 128), 256, 0, stream>>>(q_buf, proj_w, proj_b, out, M, DIMC, INNER);

  (void)in_sizes; (void)n_in; (void)out_size; (void)ws_size;
}

// Round 2
// 3571.364 us; speedup vs baseline: 1.5590x; 1.5590x over previous
//
#include <hip/hip_runtime.h>
#include <cstdint>
#include <cstddef>

// Problem constants (fixed by setup_inputs)
#define BB    16
#define NTOK  4096
#define DIMC  512
#define INNER 512
#define CTXC  256
#define HEADS 8
#define HD    64
#define AG    49
#define ASPLIT 8   // n-splits for agent attention

// ---------------- workspace layout (floats) ----------------
static const size_t Q_OFF   = 0;                                     // q / out_pre: 16*4096*512
static const size_t KV_OFF  = Q_OFF  + (size_t)BB*NTOK*INNER;        // kv: 16*4096*1024
static const size_t A2_OFF  = KV_OFF + (size_t)BB*NTOK*2*INNER;      // pooled concat: 16*49*768
static const size_t COL_OFF = A2_OFF + (size_t)BB*AG*768;            // im2col: 784*6912 (retired after conv -> reused for attn partials)
static const size_t CG_OFF  = COL_OFF+ (size_t)BB*AG*768*9;          // conv gemm out: 784*512
static const size_t AGT_OFF = CG_OFF + (size_t)BB*AG*INNER;          // agent[b,h,a,d]
static const size_t AGV_OFF = AGT_OFF+ (size_t)BB*HEADS*AG*HD;       // agent_v[b,h,a,d]
static const size_t PB_OFF  = AGV_OFF+ (size_t)BB*HEADS*AG*HD;       // pb[h,a,n]
static const size_t AB_OFF  = PB_OFF + (size_t)HEADS*AG*NTOK;        // ab[h,n,a]
// partials overlay the retired COL region:
static const size_t PNUM_OFF = COL_OFF;                              // 8*128*64*64 = 4,194,304 floats
static const size_t PL_OFF   = PNUM_OFF + (size_t)ASPLIT*128*64*64;  // 8*128*64    = 65,536 floats
// (4,259,840 < COL region's 5,419,008 floats)

// ---------------- GEMM 128x128 tile, C = A(MxK) * Bw(NxK)^T (+bias) ----------------
template <bool ADD_BIAS>
__global__ __launch_bounds__(256) void gemm128(const float* __restrict__ A,
                                               const float* __restrict__ Bw,
                                               const float* __restrict__ bias,
                                               float* __restrict__ C,
                                               int M, int Nc, int K) {
  __shared__ float As[16][128];
  __shared__ float Bs[16][128];
  const int tid = threadIdx.x;
  const int tx = tid & 15, ty = tid >> 4;
  const int bm = blockIdx.y * 128;
  const int bn = blockIdx.x * 128;
  float acc[8][8] = {};
  for (int k0 = 0; k0 < K; k0 += 16) {
#pragma unroll
    for (int l = 0; l < 2; ++l) {
      int f = tid + l * 256;            // 0..511
      int row = f >> 2;                 // 0..127
      int c4 = (f & 3) << 2;            // 0,4,8,12
      float4 av = *(const float4*)(A + (size_t)(bm + row) * K + k0 + c4);
      As[c4 + 0][row] = av.x; As[c4 + 1][row] = av.y;
      As[c4 + 2][row] = av.z; As[c4 + 3][row] = av.w;
      float4 bv = *(const float4*)(Bw + (size_t)(bn + row) * K + k0 + c4);
      Bs[c4 + 0][row] = bv.x; Bs[c4 + 1][row] = bv.y;
      Bs[c4 + 2][row] = bv.z; Bs[c4 + 3][row] = bv.w;
    }
    __syncthreads();
#pragma unroll
    for (int k = 0; k < 16; ++k) {
      float a[8], b[8];
#pragma unroll
      for (int i = 0; i < 8; ++i) a[i] = As[k][ty * 8 + i];
#pragma unroll
      for (int j = 0; j < 8; ++j) b[j] = Bs[k][tx * 8 + j];
#pragma unroll
      for (int i = 0; i < 8; ++i)
#pragma unroll
        for (int j = 0; j < 8; ++j) acc[i][j] = fmaf(a[i], b[j], acc[i][j]);
    }
    __syncthreads();
  }
#pragma unroll
  for (int i = 0; i < 8; ++i) {
    size_t m = (size_t)bm + ty * 8 + i;
    float o[8];
#pragma unroll
    for (int j = 0; j < 8; ++j) {
      o[j] = acc[i][j];
      if (ADD_BIAS) o[j] += bias[bn + tx * 8 + j];
    }
    float4 v0 = {o[0], o[1], o[2], o[3]};
    float4 v1 = {o[4], o[5], o[6], o[7]};
    *(float4*)(C + m * Nc + bn + tx * 8 + 0) = v0;
    *(float4*)(C + m * Nc + bn + tx * 8 + 4) = v1;
  }
}

// ---------------- GEMM 64x64 tile with bounds (for conv im2col GEMM) ----------------
__global__ __launch_bounds__(256) void gemm64(const float* __restrict__ A,
                                              const float* __restrict__ Bw,
                                              float* __restrict__ C,
                                              int M, int Nc, int K) {
  __shared__ float As[16][64];
  __shared__ float Bs[16][64];
  const int tid = threadIdx.x;
  const int tx = tid & 15, ty = tid >> 4;
  const int bm = blockIdx.y * 64;
  const int bn = blockIdx.x * 64;
  float acc[4][4] = {};
  for (int k0 = 0; k0 < K; k0 += 16) {
#pragma unroll
    for (int l = 0; l < 4; ++l) {
      int f = tid + l * 256;           // 0..1023
      int row = f >> 4, col = f & 15;
      As[col][row] = (bm + row < M) ? A[(size_t)(bm + row) * K + k0 + col] : 0.f;
      Bs[col][row] = (bn + row < Nc) ? Bw[(size_t)(bn + row) * K + k0 + col] : 0.f;
    }
    __syncthreads();
#pragma unroll
    for (int k = 0; k < 16; ++k) {
      float a[4], b[4];
#pragma unroll
      for (int i = 0; i < 4; ++i) a[i] = As[k][ty * 4 + i];
#pragma unroll
      for (int j = 0; j < 4; ++j) b[j] = Bs[k][tx * 4 + j];
#pragma unroll
      for (int i = 0; i < 4; ++i)
#pragma unroll
        for (int j = 0; j < 4; ++j) acc[i][j] = fmaf(a[i], b[j], acc[i][j]);
    }
    __syncthreads();
  }
#pragma unroll
  for (int i = 0; i < 4; ++i) {
    int m = bm + ty * 4 + i;
    if (m >= M) continue;
#pragma unroll
    for (int j = 0; j < 4; ++j) {
      int n = bn + tx * 4 + j;
      if (n < Nc) C[(size_t)m * Nc + n] = acc[i][j];
    }
  }
}

// ---------------- overlapping avg-pool of q and context -> A2[b,49,768] ----------------
__global__ void pool_kernel(const float* __restrict__ q, const float* __restrict__ ctx,
                            float* __restrict__ A2) {
  const int p = blockIdx.x;   // 0..48
  const int b = blockIdx.y;
  const int i = p / 7, j = p % 7;
  const int hs = i * 64 / 7, he = ((i + 1) * 64 + 6) / 7;
  const int ws = j * 64 / 7, we = ((j + 1) * 64 + 6) / 7;
  const float inv = 1.f / (float)((he - hs) * (we - ws));
  for (int ch = threadIdx.x; ch < 768; ch += 256) {
    float s = 0.f;
    if (ch < 512) {
      for (int h = hs; h < he; ++h)
        for (int w = ws; w < we; ++w)
          s += q[((size_t)(b * NTOK) + h * 64 + w) * INNER + ch];
    } else {
      int cc = ch - 512;
      for (int h = hs; h < he; ++h)
        for (int w = ws; w < we; ++w)
          s += ctx[((size_t)(b * NTOK) + h * 64 + w) * CTXC + cc];
    }
    A2[((size_t)b * AG + p) * 768 + ch] = s * inv;
  }
}

// ---------------- im2col of scrambled agent_in: Col[b*49+p][ic*9+ky*3+kx] ----------------
__global__ void im2col_kernel(const float* __restrict__ A2, float* __restrict__ Col) {
  int idx = blockIdx.x * 256 + threadIdx.x;    // 784*6912
  if (idx >= 784 * 6912) return;
  int r = idx / 6912, t = idx % 6912;
  int ic = t / 9, ky = (t % 9) / 3, kx = t % 3;
  int b = r / AG, p = r % AG;
  int y = p / 7 + ky - 1, x = p % 7 + kx - 1;
  float v = 0.f;
  if (y >= 0 && y < 7 && x >= 0 && x < 7) {
    int g = ic * 49 + y * 7 + x;              // agent_in[b][ic][y][x] = A2[b][g/768][g%768]
    v = A2[((size_t)b * AG + g / 768) * 768 + (g % 768)];
  }
  Col[(size_t)idx] = v;
}

// ---------------- scramble conv output -> agent[b,h,a,d] (+conv bias) ----------------
__global__ void agent_scatter_kernel(const float* __restrict__ Cg, const float* __restrict__ conv_b,
                                     float* __restrict__ agent) {
  int idx = blockIdx.x * 256 + threadIdx.x;   // 16*8*49*64
  if (idx >= BB * HEADS * AG * HD) return;
  int d = idx & 63;
  int a = (idx >> 6) % AG;
  int h = (idx / (64 * AG)) % HEADS;
  int b = idx / (64 * AG * HEADS);
  int f = a * 512 + h * 64 + d;               // reshape (b,512,49)->(b,49,8,64)
  int oc = f / 49, p = f % 49;
  agent[idx] = Cg[((size_t)b * AG + p) * INNER + oc] + conv_b[oc];
}

// ---------------- jax bilinear resize 7->64 (half-pixel, renorm == clamp) ----------------
__device__ inline float bilinear7(const float* __restrict__ Bm, int y, int x) {
  float fy = (y + 0.5f) * (7.f / 64.f) - 0.5f;
  float fx = (x + 0.5f) * (7.f / 64.f) - 0.5f;
  fy = fminf(fmaxf(fy, 0.f), 6.f);
  fx = fminf(fmaxf(fx, 0.f), 6.f);
  int y0 = min((int)floorf(fy), 5);
  int x0 = min((int)floorf(fx), 5);
  float ty = fy - y0, tx = fx - x0;
  float v00 = Bm[y0 * 7 + x0],     v01 = Bm[y0 * 7 + x0 + 1];
  float v10 = Bm[(y0 + 1) * 7 + x0], v11 = Bm[(y0 + 1) * 7 + x0 + 1];
  return (1.f - ty) * ((1.f - tx) * v00 + tx * v01) + ty * ((1.f - tx) * v10 + tx * v11);
}

// pb[h][a][n] = resize(an_bias[h,a])(y,x) + ah[h,a,y] + aw[h,a,x]
__global__ void pb_kernel(const float* __restrict__ an_bias, const float* __restrict__ ah,
                          const float* __restrict__ aw, float* __restrict__ pb) {
  int idx = blockIdx.x * 256 + threadIdx.x;   // 8*49*4096
  if (idx >= HEADS * AG * NTOK) return;
  int nn = idx & (NTOK - 1);
  int a = (idx / NTOK) % AG;
  int h = idx / (NTOK * AG);
  int y = nn >> 6, x = nn & 63;
  float v = bilinear7(an_bias + ((size_t)h * AG + a) * 49, y, x);
  v += ah[((size_t)h * AG + a) * 64 + y] + aw[((size_t)h * AG + a) * 64 + x];
  pb[idx] = v;
}

// ab[h][n][a] = resize(na_bias[h,a])(y,x) + ha[h,y,a] + wa[h,x,a]
__global__ void ab_kernel(const float* __restrict__ na_bias, const float* __restrict__ ha,
                          const float* __restrict__ wa, float* __restrict__ ab) {
  int idx = blockIdx.x * 256 + threadIdx.x;   // 8*4096*49
  if (idx >= HEADS * NTOK * AG) return;
  int a = idx % AG;
  int nn = (idx / AG) & (NTOK - 1);
  int h = idx / (AG * NTOK);
  int y = nn >> 6, x = nn & 63;
  float v = bilinear7(na_bias + ((size_t)h * AG + a) * 49, y, x);
  v += ha[((size_t)h * 64 + y) * AG + a] + wa[((size_t)h * 64 + x) * AG + a];
  ab[idx] = v;
}

// ---------------- agent attention, flash-style, all 49 agents per block ----------------
// grid (ASPLIT, HEADS, BB); each block: 512 tokens, S = agent*scale . k^T + pb,
// e = exp(S) (no max: |S| << 80, softmax shift-invariant), accumulate sum(e*v), sum(e).
// Partials to global; combine kernel divides.
__global__ __launch_bounds__(256, 2) void agent_attn_s(const float* __restrict__ kv,
                                                       const float* __restrict__ agent,
                                                       const float* __restrict__ pb,
                                                       float* __restrict__ part_num,
                                                       float* __restrict__ part_l) {
  const int split = blockIdx.x;                 // 0..ASPLIT-1
  const int h = blockIdx.y, b = blockIdx.z;
  const int bh = b * HEADS + h;
  __shared__ float agT[64][68];                 // [d][a]  (a padded to 64 with zeros)
  __shared__ float ktT[64][68];                 // [d][n]
  __shared__ float vt[64][68];                  // [n][d]
  __shared__ float eT[64][68];                  // [n][a]
  const int tid = threadIdx.x;
  const int tx = tid & 15, ty = tid >> 4;       // ty -> a-quad, tx -> n/d-quad

  // stage agent transposed (scaled)
  for (int idx = tid; idx < AG * 16; idx += 256) {
    int a = idx >> 4, d0 = (idx & 15) << 2;
    float4 v4 = *(const float4*)(agent + ((size_t)bh * AG + a) * HD + d0);
    agT[d0 + 0][a] = v4.x * 0.125f; agT[d0 + 1][a] = v4.y * 0.125f;
    agT[d0 + 2][a] = v4.z * 0.125f; agT[d0 + 3][a] = v4.w * 0.125f;
  }
  for (int idx = tid; idx < 64 * 15; idx += 256) {    // zero-pad a = 49..63
    int d = idx / 15, a = AG + idx % 15;
    agT[d][a] = 0.f;
  }

  float accR[4][4] = {};                        // [a-quad][d-quad]
  float lR[4] = {};                             // per a-quad (replicated over tx)

  const float* kb = kv + (size_t)b * NTOK * 1024 + h * 64;   // k rows, stride 1024
  const float* vb = kb + 512;                                 // v rows
  const float* pbh = pb + (size_t)h * AG * NTOK;

  const int nrow = tid & 63, dq = tid >> 6;     // staging mapping

  for (int c = 0; c < 8; ++c) {
    const int n0 = split * 512 + c * 64;
    // ---- stage k (transposed) and v (natural) ----
#pragma unroll
    for (int i = 0; i < 4; ++i) {
      int d = dq * 16 + i * 4;
      float4 kk = *(const float4*)(kb + (size_t)(n0 + nrow) * 1024 + d);
      ktT[d + 0][nrow] = kk.x; ktT[d + 1][nrow] = kk.y;
      ktT[d + 2][nrow] = kk.z; ktT[d + 3][nrow] = kk.w;
      float4 vv = *(const float4*)(vb + (size_t)(n0 + nrow) * 1024 + d);
      *(float4*)&vt[nrow][d] = vv;
    }
    __syncthreads();
    // ---- S = agT^T . ktT  (64a x 64n tile, outer product over d) ----
    float s[4][4] = {};
#pragma unroll 4
    for (int d = 0; d < 64; ++d) {
      float4 a4 = *(float4*)&agT[d][ty * 4];
      float4 k4 = *(float4*)&ktT[d][tx * 4];
      s[0][0] = fmaf(a4.x, k4.x, s[0][0]); s[0][1] = fmaf(a4.x, k4.y, s[0][1]);
      s[0][2] = fmaf(a4.x, k4.z, s[0][2]); s[0][3] = fmaf(a4.x, k4.w, s[0][3]);
      s[1][0] = fmaf(a4.y, k4.x, s[1][0]); s[1][1] = fmaf(a4.y, k4.y, s[1][1]);
      s[1][2] = fmaf(a4.y, k4.z, s[1][2]); s[1][3] = fmaf(a4.y, k4.w, s[1][3]);
      s[2][0] = fmaf(a4.z, k4.x, s[2][0]); s[2][1] = fmaf(a4.z, k4.y, s[2][1]);
      s[2][2] = fmaf(a4.z, k4.z, s[2][2]); s[2][3] = fmaf(a4.z, k4.w, s[2][3]);
      s[3][0] = fmaf(a4.w, k4.x, s[3][0]); s[3][1] = fmaf(a4.w, k4.y, s[3][1]);
      s[3][2] = fmaf(a4.w, k4.z, s[3][2]); s[3][3] = fmaf(a4.w, k4.w, s[3][3]);
    }
    // ---- e = exp(s + pb); accumulate row sums ----
#pragma unroll
    for (int i = 0; i < 4; ++i) {
      int a = ty * 4 + i;
      int ac = a < AG ? a : AG - 1;             // clamp (padded rows: values unused)
      float4 p4 = *(const float4*)(pbh + (size_t)ac * NTOK + n0 + tx * 4);
      float e0 = __expf(s[i][0] + p4.x);
      float e1 = __expf(s[i][1] + p4.y);
      float e2 = __expf(s[i][2] + p4.z);
      float e3 = __expf(s[i][3] + p4.w);
      lR[i] += e0 + e1 + e2 + e3;
      eT[tx * 4 + 0][a] = e0; eT[tx * 4 + 1][a] = e1;
      eT[tx * 4 + 2][a] = e2; eT[tx * 4 + 3][a] = e3;
    }
    __syncthreads();
    // ---- accR += eT^T . vt  (outer product over n) ----
#pragma unroll 4
    for (int n = 0; n < 64; ++n) {
      float4 e4 = *(float4*)&eT[n][ty * 4];
      float4 v4 = *(float4*)&vt[n][tx * 4];
      accR[0][0] = fmaf(e4.x, v4.x, accR[0][0]); accR[0][1] = fmaf(e4.x, v4.y, accR[0][1]);
      accR[0][2] = fmaf(e4.x, v4.z, accR[0][2]); accR[0][3] = fmaf(e4.x, v4.w, accR[0][3]);
      accR[1][0] = fmaf(e4.y, v4.x, accR[1][0]); accR[1][1] = fmaf(e4.y, v4.y, accR[1][1]);
      accR[1][2] = fmaf(e4.y, v4.z, accR[1][2]); accR[1][3] = fmaf(e4.y, v4.w, accR[1][3]);
      accR[2][0] = fmaf(e4.z, v4.x, accR[2][0]); accR[2][1] = fmaf(e4.z, v4.y, accR[2][1]);
      accR[2][2] = fmaf(e4.z, v4.z, accR[2][2]); accR[2][3] = fmaf(e4.z, v4.w, accR[2][3]);
      accR[3][0] = fmaf(e4.w, v4.x, accR[3][0]); accR[3][1] = fmaf(e4.w, v4.y, accR[3][1]);
      accR[3][2] = fmaf(e4.w, v4.z, accR[3][2]); accR[3][3] = fmaf(e4.w, v4.w, accR[3][3]);
    }
    __syncthreads();
  }
  // ---- reduce l over the 16 tx lanes of each a-group (lanes are contiguous) ----
#pragma unroll
  for (int i = 0; i < 4; ++i) {
    float l = lR[i];
    l += __shfl_xor(l, 1, 64); l += __shfl_xor(l, 2, 64);
    l += __shfl_xor(l, 4, 64); l += __shfl_xor(l, 8, 64);
    lR[i] = l;
  }
  // ---- write partials ----
  float* pn = part_num + ((size_t)(split * 128 + bh)) * 64 * 64;
  float* pl = part_l + (size_t)(split * 128 + bh) * 64;
#pragma unroll
  for (int i = 0; i < 4; ++i) {
    int a = ty * 4 + i;
    if (a < AG) {
      float4 o = {accR[i][0], accR[i][1], accR[i][2], accR[i][3]};
      *(float4*)(pn + a * 64 + tx * 4) = o;
      if (tx == 0) pl[a] = lR[i];
    }
  }
}

__global__ void agent_attn_combine(const float* __restrict__ part_num,
                                   const float* __restrict__ part_l,
                                   float* __restrict__ agent_v) {
  int idx = blockIdx.x * 256 + threadIdx.x;   // 128*49*64
  if (idx >= 128 * AG * 64) return;
  int d = idx & 63;
  int a = (idx >> 6) % AG;
  int bh = idx / (AG * 64);
  float num = 0.f, l = 0.f;
#pragma unroll
  for (int s = 0; s < ASPLIT; ++s) {
    num += part_num[((size_t)(s * 128 + bh)) * 4096 + a * 64 + d];
    l += part_l[(size_t)(s * 128 + bh) * 64 + a];
  }
  agent_v[((size_t)bh * AG + a) * HD + d] = num / l;
}

// ---------------- q attention fused: softmax_a(q*scale . agent^T + ab) @ agent_v ----------------
// overwrites q buffer in place with out_pre[b,n,h*64+d]
__global__ __launch_bounds__(256) void q_attn_kernel(const float* __restrict__ agent,
                                                     const float* __restrict__ agent_v,
                                                     const float* __restrict__ ab,
                                                     float* __restrict__ q) {
  const int tile = blockIdx.x;   // 16 tiles of 256 tokens
  const int h = blockIdx.y, b = blockIdx.z;
  __shared__ float ag[AG][HD];
  __shared__ float av[AG][HD];
  const int tid = threadIdx.x;
  const size_t base = ((size_t)(b * HEADS + h)) * AG * HD;
  for (int t = tid; t < AG * HD; t += 256) {
    ag[t / HD][t % HD] = agent[base + t] * 0.125f;
    av[t / HD][t % HD] = agent_v[base + t];
  }
  __syncthreads();
  const int nn = tile * 256 + tid;
  float* qrow = q + ((size_t)(b * NTOK) + nn) * INNER + h * 64;
  float qr[64];
#pragma unroll
  for (int d = 0; d < 64; d += 4) {
    float4 v4 = *(const float4*)(qrow + d);
    qr[d] = v4.x; qr[d + 1] = v4.y; qr[d + 2] = v4.z; qr[d + 3] = v4.w;
  }
  const float* abr = ab + ((size_t)h * NTOK + nn) * AG;
  float scr[AG];
  float m = -3.4e38f;
  for (int a = 0; a < AG; ++a) {
    float dot = 0.f;
#pragma unroll
    for (int d = 0; d < 64; ++d) dot = fmaf(qr[d], ag[a][d], dot);
    float s = dot + abr[a];
    scr[a] = s;
    m = fmaxf(m, s);
  }
  float l = 0.f;
  for (int a = 0; a < AG; ++a) {
    float e = __expf(scr[a] - m);
    scr[a] = e;
    l += e;
  }
  const float invl = 1.f / l;
#pragma unroll
  for (int d = 0; d < 64; ++d) qr[d] = 0.f;
  for (int a = 0; a < AG; ++a) {
    float p = scr[a] * invl;
#pragma unroll
    for (int d = 0; d < 64; ++d) qr[d] = fmaf(p, av[a][d], qr[d]);
  }
#pragma unroll
  for (int d = 0; d < 64; d += 4) {
    float4 v4 = {qr[d], qr[d + 1], qr[d + 2], qr[d + 3]};
    *(float4*)(qrow + d) = v4;
  }
}

// ---------------- depthwise 3x3 conv on v, added into out_pre ----------------
__global__ void dwc_kernel(const float* __restrict__ kv, const float* __restrict__ dwc_w,
                           const float* __restrict__ dwc_b, float* __restrict__ outp) {
  size_t idx = (size_t)blockIdx.x * 256 + threadIdx.x;   // 16*4096*512
  int c = (int)(idx & 511);
  size_t r = idx >> 9;
  int x = (int)(r & 63);
  int y = (int)((r >> 6) & 63);
  int b = (int)(r >> 12);
  const float* vb = kv + (size_t)b * NTOK * 1024 + 512 + c;
  float s = dwc_b[c];
#pragma unroll
  for (int ky = 0; ky < 3; ++ky) {
    int yy = y + ky - 1;
    if (yy < 0 || yy > 63) continue;
#pragma unroll
    for (int kx = 0; kx < 3; ++kx) {
      int xx = x + kx - 1;
      if (xx < 0 || xx > 63) continue;
      s = fmaf(dwc_w[c * 9 + ky * 3 + kx], vb[(size_t)(yy * 64 + xx) * 1024], s);
    }
  }
  outp[idx] += s;
}

// ---------------- host launcher ----------------
extern "C" void kernel_launch(void* const* d_in, const int* in_sizes, int n_in,
                              void* d_out, int out_size, void* d_ws, size_t ws_size,
                              hipStream_t stream) {
  const float* x       = (const float*)d_in[0];
  const float* context = (const float*)d_in[1];
  const float* q_w     = (const float*)d_in[2];
  const float* kv_w    = (const float*)d_in[3];
  const float* proj_w  = (const float*)d_in[4];
  const float* proj_b  = (const float*)d_in[5];
  const float* conv_w  = (const float*)d_in[6];
  const float* conv_b  = (const float*)d_in[7];
  const float* dwc_w   = (const float*)d_in[8];
  const float* dwc_b   = (const float*)d_in[9];
  const float* an_bias = (const float*)d_in[10];
  const float* na_bias = (const float*)d_in[11];
  const float* ah_bias = (const float*)d_in[12];
  const float* aw_bias = (const float*)d_in[13];
  const float* ha_bias = (const float*)d_in[14];
  const float* wa_bias = (const float*)d_in[15];
  float* out = (float*)d_out;
  float* wsf = (float*)d_ws;

  float* q_buf  = wsf + Q_OFF;    // later becomes out_pre
  float* kv_buf = wsf + KV_OFF;
  float* A2     = wsf + A2_OFF;
  float* Col    = wsf + COL_OFF;
  float* Cg     = wsf + CG_OFF;
  float* agent  = wsf + AGT_OFF;
  float* agentv = wsf + AGV_OFF;
  float* pb     = wsf + PB_OFF;
  float* ab     = wsf + AB_OFF;
  float* pnum   = wsf + PNUM_OFF;  // overlays Col (retired by then)
  float* pl     = wsf + PL_OFF;

  const int M = BB * NTOK;   // 65536

  // 1. q = x @ q_w^T
  gemm128<false><<<dim3(INNER / 128, M / 128), 256, 0, stream>>>(x, q_w, nullptr, q_buf, M, INNER, DIMC);
  // 2. kv = x @ kv_w^T
  gemm128<false><<<dim3(2 * INNER / 128, M / 128), 256, 0, stream>>>(x, kv_w, nullptr, kv_buf, M, 2 * INNER, DIMC);
  // 3. pooled concat
  pool_kernel<<<dim3(AG, BB), 256, 0, stream>>>(q_buf, context, A2);
  // 4. im2col
  im2col_kernel<<<(784 * 6912 + 255) / 256, 256, 0, stream>>>(A2, Col);
  // 5. conv as GEMM: Cg[784][512] = Col[784][6912] @ conv_w[512][6912]^T
  gemm64<<<dim3((INNER + 63) / 64, (784 + 63) / 64), 256, 0, stream>>>(Col, conv_w, Cg, 784, INNER, 6912);
  // 6. scramble + conv bias -> agent[b,h,a,d]
  agent_scatter_kernel<<<(BB * HEADS * AG * HD + 255) / 256, 256, 0, stream>>>(Cg, conv_b, agent);
  // 7./8. bias tables
  pb_kernel<<<(HEADS * AG * NTOK + 255) / 256, 256, 0, stream>>>(an_bias, ah_bias, aw_bias, pb);
  ab_kernel<<<(HEADS * NTOK * AG + 255) / 256, 256, 0, stream>>>(na_bias, ha_bias, wa_bias, ab);
  // 9. agent attention -> partials -> agent_v   (Col region retired, reused for partials)
  agent_attn_s<<<dim3(ASPLIT, HEADS, BB), 256, 0, stream>>>(kv_buf, agent, pb, pnum, pl);
  agent_attn_combine<<<(128 * AG * 64 + 255) / 256, 256, 0, stream>>>(pnum, pl, agentv);
  // 10. q attention (q_buf overwritten with out_pre)
  q_attn_kernel<<<dim3(NTOK / 256, HEADS, BB), 256, 0, stream>>>(agent, agentv, ab, q_buf);
  // 11. depthwise conv on v added into out_pre
  dwc_kernel<<<(BB * NTOK * INNER) / 256, 256, 0, stream>>>(kv_buf, dwc_w, dwc_b, q_buf);
  // 12. final projection with bias
  gemm128<true><<<dim3(DIMC / 128, M / 128), 256, 0, stream>>>(q_buf, proj_w, proj_b, out, M, DIMC, INNER);

  (void)in_sizes; (void)n_in; (void)out_size; (void)ws_size;
}

// Round 3
// 2875.967 us; speedup vs baseline: 1.9360x; 1.2418x over previous
//
#include <hip/hip_runtime.h>
#include <cstdint>
#include <cstddef>

// Problem constants (fixed by setup_inputs)
#define BB    16
#define NTOK  4096
#define DIMC  512
#define INNER 512
#define CTXC  256
#define HEADS 8
#define HD    64
#define AG    49
#define ASPLIT 8   // n-splits for agent attention
#define CONVK 6912
#define CKS   16   // k-splits for conv GEMM (chunk = 432 = 27*16)

// ---------------- workspace layout (floats) ----------------
static const size_t Q_OFF   = 0;                                     // q / out_pre: 16*4096*512
static const size_t KV_OFF  = Q_OFF  + (size_t)BB*NTOK*INNER;        // kv: 16*4096*1024
static const size_t A2_OFF  = KV_OFF + (size_t)BB*NTOK*2*INNER;      // pooled concat: 16*49*768
static const size_t COL_OFF = A2_OFF + (size_t)BB*AG*768;            // im2col: 784*6912 (retired after conv -> reused for attn partials)
static const size_t CG_OFF  = COL_OFF+ (size_t)BB*AG*768*9;          // conv gemm out: 784*512
static const size_t AGT_OFF = CG_OFF + (size_t)BB*AG*INNER;          // agent[b,h,a,d]
static const size_t AGV_OFF = AGT_OFF+ (size_t)BB*HEADS*AG*HD;       // agent_v[b,h,a,d]
static const size_t PB_OFF  = AGV_OFF+ (size_t)BB*HEADS*AG*HD;       // pb[h,a,n]
static const size_t AB_OFF  = PB_OFF + (size_t)HEADS*AG*NTOK;        // ab[h,n,a]
// partials overlay the retired COL region:
static const size_t PNUM_OFF = COL_OFF;                              // 8*128*64*64 = 4,194,304 floats
static const size_t PL_OFF   = PNUM_OFF + (size_t)ASPLIT*128*64*64;  // 8*128*64    = 65,536 floats
// (4,259,840 < COL region's 5,419,008 floats)

// ---------------- GEMM 128x128 tile, C = A(MxK) * Bw(NxK)^T (+bias) ----------------
template <bool ADD_BIAS>
__global__ __launch_bounds__(256) void gemm128(const float* __restrict__ A,
                                               const float* __restrict__ Bw,
                                               const float* __restrict__ bias,
                                               float* __restrict__ C,
                                               int M, int Nc, int K) {
  __shared__ float As[16][128];
  __shared__ float Bs[16][128];
  const int tid = threadIdx.x;
  const int tx = tid & 15, ty = tid >> 4;
  const int bm = blockIdx.y * 128;
  const int bn = blockIdx.x * 128;
  float acc[8][8] = {};
  for (int k0 = 0; k0 < K; k0 += 16) {
#pragma unroll
    for (int l = 0; l < 2; ++l) {
      int f = tid + l * 256;            // 0..511
      int row = f >> 2;                 // 0..127
      int c4 = (f & 3) << 2;            // 0,4,8,12
      float4 av = *(const float4*)(A + (size_t)(bm + row) * K + k0 + c4);
      As[c4 + 0][row] = av.x; As[c4 + 1][row] = av.y;
      As[c4 + 2][row] = av.z; As[c4 + 3][row] = av.w;
      float4 bv = *(const float4*)(Bw + (size_t)(bn + row) * K + k0 + c4);
      Bs[c4 + 0][row] = bv.x; Bs[c4 + 1][row] = bv.y;
      Bs[c4 + 2][row] = bv.z; Bs[c4 + 3][row] = bv.w;
    }
    __syncthreads();
#pragma unroll
    for (int k = 0; k < 16; ++k) {
      float a[8], b[8];
#pragma unroll
      for (int i = 0; i < 8; ++i) a[i] = As[k][ty * 8 + i];
#pragma unroll
      for (int j = 0; j < 8; ++j) b[j] = Bs[k][tx * 8 + j];
#pragma unroll
      for (int i = 0; i < 8; ++i)
#pragma unroll
        for (int j = 0; j < 8; ++j) acc[i][j] = fmaf(a[i], b[j], acc[i][j]);
    }
    __syncthreads();
  }
#pragma unroll
  for (int i = 0; i < 8; ++i) {
    size_t m = (size_t)bm + ty * 8 + i;
    float o[8];
#pragma unroll
    for (int j = 0; j < 8; ++j) {
      o[j] = acc[i][j];
      if (ADD_BIAS) o[j] += bias[bn + tx * 8 + j];
    }
    float4 v0 = {o[0], o[1], o[2], o[3]};
    float4 v1 = {o[4], o[5], o[6], o[7]};
    *(float4*)(C + m * Nc + bn + tx * 8 + 0) = v0;
    *(float4*)(C + m * Nc + bn + tx * 8 + 4) = v1;
  }
}

// ---------------- zero-fill (graph-capture-safe memset) ----------------
__global__ void zero_kernel(float* __restrict__ p, int n) {
  int i = blockIdx.x * 256 + threadIdx.x;
  if (i < n) p[i] = 0.f;
}

// ---------------- conv GEMM, split-K + atomics: Cg[784][512] += Col[784][6912] @ W[512][6912]^T ----------------
// grid (8 n-tiles, 13 m-tiles, CKS k-splits); 64x64 tile, 4x4 acc/thread.
__global__ __launch_bounds__(256) void conv_gemm_splitk(const float* __restrict__ A,
                                                        const float* __restrict__ Bw,
                                                        float* __restrict__ C) {
  __shared__ float As[16][72];   // [k][row], pad 72: 4-way residual conflict (~free)
  __shared__ float Bs[16][72];
  const int tid = threadIdx.x;
  const int tx = tid & 15, ty = tid >> 4;
  const int bn = blockIdx.x * 64;
  const int bm = blockIdx.y * 64;
  const int k_begin = blockIdx.z * (CONVK / CKS);
  const int k_end = k_begin + (CONVK / CKS);
  const int row = tid >> 2, c4 = (tid & 3) << 2;
  float acc[4][4] = {};
  for (int k0 = k_begin; k0 < k_end; k0 += 16) {
    {
      int m = bm + row;
      float4 av = {0.f, 0.f, 0.f, 0.f};
      if (m < 784) av = *(const float4*)(A + (size_t)m * CONVK + k0 + c4);
      As[c4 + 0][row] = av.x; As[c4 + 1][row] = av.y;
      As[c4 + 2][row] = av.z; As[c4 + 3][row] = av.w;
      float4 bv = *(const float4*)(Bw + (size_t)(bn + row) * CONVK + k0 + c4);
      Bs[c4 + 0][row] = bv.x; Bs[c4 + 1][row] = bv.y;
      Bs[c4 + 2][row] = bv.z; Bs[c4 + 3][row] = bv.w;
    }
    __syncthreads();
#pragma unroll
    for (int k = 0; k < 16; ++k) {
      float a[4], b[4];
#pragma unroll
      for (int i = 0; i < 4; ++i) a[i] = As[k][ty * 4 + i];
#pragma unroll
      for (int j = 0; j < 4; ++j) b[j] = Bs[k][tx * 4 + j];
#pragma unroll
      for (int i = 0; i < 4; ++i)
#pragma unroll
        for (int j = 0; j < 4; ++j) acc[i][j] = fmaf(a[i], b[j], acc[i][j]);
    }
    __syncthreads();
  }
#pragma unroll
  for (int i = 0; i < 4; ++i) {
    int m = bm + ty * 4 + i;
    if (m >= 784) continue;
#pragma unroll
    for (int j = 0; j < 4; ++j)
      atomicAdd(C + (size_t)m * INNER + bn + tx * 4 + j, acc[i][j]);
  }
}

// ---------------- overlapping avg-pool of q and context -> A2[b,49,768] ----------------
__global__ void pool_kernel(const float* __restrict__ q, const float* __restrict__ ctx,
                            float* __restrict__ A2) {
  const int p = blockIdx.x;   // 0..48
  const int b = blockIdx.y;
  const int i = p / 7, j = p % 7;
  const int hs = i * 64 / 7, he = ((i + 1) * 64 + 6) / 7;
  const int ws = j * 64 / 7, we = ((j + 1) * 64 + 6) / 7;
  const float inv = 1.f / (float)((he - hs) * (we - ws));
  for (int ch = threadIdx.x; ch < 768; ch += 256) {
    float s = 0.f;
    if (ch < 512) {
      for (int h = hs; h < he; ++h)
        for (int w = ws; w < we; ++w)
          s += q[((size_t)(b * NTOK) + h * 64 + w) * INNER + ch];
    } else {
      int cc = ch - 512;
      for (int h = hs; h < he; ++h)
        for (int w = ws; w < we; ++w)
          s += ctx[((size_t)(b * NTOK) + h * 64 + w) * CTXC + cc];
    }
    A2[((size_t)b * AG + p) * 768 + ch] = s * inv;
  }
}

// ---------------- im2col of scrambled agent_in: Col[b*49+p][ic*9+ky*3+kx] ----------------
__global__ void im2col_kernel(const float* __restrict__ A2, float* __restrict__ Col) {
  int idx = blockIdx.x * 256 + threadIdx.x;    // 784*6912
  if (idx >= 784 * 6912) return;
  int r = idx / 6912, t = idx % 6912;
  int ic = t / 9, ky = (t % 9) / 3, kx = t % 3;
  int b = r / AG, p = r % AG;
  int y = p / 7 + ky - 1, x = p % 7 + kx - 1;
  float v = 0.f;
  if (y >= 0 && y < 7 && x >= 0 && x < 7) {
    int g = ic * 49 + y * 7 + x;              // agent_in[b][ic][y][x] = A2[b][g/768][g%768]
    v = A2[((size_t)b * AG + g / 768) * 768 + (g % 768)];
  }
  Col[(size_t)idx] = v;
}

// ---------------- scramble conv output -> agent[b,h,a,d] (+conv bias) ----------------
__global__ void agent_scatter_kernel(const float* __restrict__ Cg, const float* __restrict__ conv_b,
                                     float* __restrict__ agent) {
  int idx = blockIdx.x * 256 + threadIdx.x;   // 16*8*49*64
  if (idx >= BB * HEADS * AG * HD) return;
  int d = idx & 63;
  int a = (idx >> 6) % AG;
  int h = (idx / (64 * AG)) % HEADS;
  int b = idx / (64 * AG * HEADS);
  int f = a * 512 + h * 64 + d;               // reshape (b,512,49)->(b,49,8,64)
  int oc = f / 49, p = f % 49;
  agent[idx] = Cg[((size_t)b * AG + p) * INNER + oc] + conv_b[oc];
}

// ---------------- jax bilinear resize 7->64 (half-pixel, renorm == clamp) ----------------
__device__ inline float bilinear7(const float* __restrict__ Bm, int y, int x) {
  float fy = (y + 0.5f) * (7.f / 64.f) - 0.5f;
  float fx = (x + 0.5f) * (7.f / 64.f) - 0.5f;
  fy = fminf(fmaxf(fy, 0.f), 6.f);
  fx = fminf(fmaxf(fx, 0.f), 6.f);
  int y0 = min((int)floorf(fy), 5);
  int x0 = min((int)floorf(fx), 5);
  float ty = fy - y0, tx = fx - x0;
  float v00 = Bm[y0 * 7 + x0],     v01 = Bm[y0 * 7 + x0 + 1];
  float v10 = Bm[(y0 + 1) * 7 + x0], v11 = Bm[(y0 + 1) * 7 + x0 + 1];
  return (1.f - ty) * ((1.f - tx) * v00 + tx * v01) + ty * ((1.f - tx) * v10 + tx * v11);
}

// pb[h][a][n] = resize(an_bias[h,a])(y,x) + ah[h,a,y] + aw[h,a,x]
__global__ void pb_kernel(const float* __restrict__ an_bias, const float* __restrict__ ah,
                          const float* __restrict__ aw, float* __restrict__ pb) {
  int idx = blockIdx.x * 256 + threadIdx.x;   // 8*49*4096
  if (idx >= HEADS * AG * NTOK) return;
  int nn = idx & (NTOK - 1);
  int a = (idx / NTOK) % AG;
  int h = idx / (NTOK * AG);
  int y = nn >> 6, x = nn & 63;
  float v = bilinear7(an_bias + ((size_t)h * AG + a) * 49, y, x);
  v += ah[((size_t)h * AG + a) * 64 + y] + aw[((size_t)h * AG + a) * 64 + x];
  pb[idx] = v;
}

// ab[h][n][a] = resize(na_bias[h,a])(y,x) + ha[h,y,a] + wa[h,x,a]
__global__ void ab_kernel(const float* __restrict__ na_bias, const float* __restrict__ ha,
                          const float* __restrict__ wa, float* __restrict__ ab) {
  int idx = blockIdx.x * 256 + threadIdx.x;   // 8*4096*49
  if (idx >= HEADS * NTOK * AG) return;
  int a = idx % AG;
  int nn = (idx / AG) & (NTOK - 1);
  int h = idx / (AG * NTOK);
  int y = nn >> 6, x = nn & 63;
  float v = bilinear7(na_bias + ((size_t)h * AG + a) * 49, y, x);
  v += ha[((size_t)h * 64 + y) * AG + a] + wa[((size_t)h * 64 + x) * AG + a];
  ab[idx] = v;
}

// ---------------- agent attention, flash-style, all 49 agents per block ----------------
__global__ __launch_bounds__(256, 2) void agent_attn_s(const float* __restrict__ kv,
                                                       const float* __restrict__ agent,
                                                       const float* __restrict__ pb,
                                                       float* __restrict__ part_num,
                                                       float* __restrict__ part_l) {
  const int split = blockIdx.x;                 // 0..ASPLIT-1
  const int h = blockIdx.y, b = blockIdx.z;
  const int bh = b * HEADS + h;
  __shared__ float agT[64][68];                 // [d][a]  (a padded to 64 with zeros)
  __shared__ float ktT[64][68];                 // [d][n]
  __shared__ float vt[64][68];                  // [n][d]
  __shared__ float eT[64][68];                  // [n][a]
  const int tid = threadIdx.x;
  const int tx = tid & 15, ty = tid >> 4;       // ty -> a-quad, tx -> n/d-quad

  for (int idx = tid; idx < AG * 16; idx += 256) {
    int a = idx >> 4, d0 = (idx & 15) << 2;
    float4 v4 = *(const float4*)(agent + ((size_t)bh * AG + a) * HD + d0);
    agT[d0 + 0][a] = v4.x * 0.125f; agT[d0 + 1][a] = v4.y * 0.125f;
    agT[d0 + 2][a] = v4.z * 0.125f; agT[d0 + 3][a] = v4.w * 0.125f;
  }
  for (int idx = tid; idx < 64 * 15; idx += 256) {    // zero-pad a = 49..63
    int d = idx / 15, a = AG + idx % 15;
    agT[d][a] = 0.f;
  }

  float accR[4][4] = {};                        // [a-quad][d-quad]
  float lR[4] = {};                             // per a-quad (replicated over tx)

  const float* kb = kv + (size_t)b * NTOK * 1024 + h * 64;   // k rows, stride 1024
  const float* vb = kb + 512;                                 // v rows
  const float* pbh = pb + (size_t)h * AG * NTOK;

  const int nrow = tid & 63, dq = tid >> 6;     // staging mapping

  for (int c = 0; c < 8; ++c) {
    const int n0 = split * 512 + c * 64;
#pragma unroll
    for (int i = 0; i < 4; ++i) {
      int d = dq * 16 + i * 4;
      float4 kk = *(const float4*)(kb + (size_t)(n0 + nrow) * 1024 + d);
      ktT[d + 0][nrow] = kk.x; ktT[d + 1][nrow] = kk.y;
      ktT[d + 2][nrow] = kk.z; ktT[d + 3][nrow] = kk.w;
      float4 vv = *(const float4*)(vb + (size_t)(n0 + nrow) * 1024 + d);
      *(float4*)&vt[nrow][d] = vv;
    }
    __syncthreads();
    float s[4][4] = {};
#pragma unroll 4
    for (int d = 0; d < 64; ++d) {
      float4 a4 = *(float4*)&agT[d][ty * 4];
      float4 k4 = *(float4*)&ktT[d][tx * 4];
      s[0][0] = fmaf(a4.x, k4.x, s[0][0]); s[0][1] = fmaf(a4.x, k4.y, s[0][1]);
      s[0][2] = fmaf(a4.x, k4.z, s[0][2]); s[0][3] = fmaf(a4.x, k4.w, s[0][3]);
      s[1][0] = fmaf(a4.y, k4.x, s[1][0]); s[1][1] = fmaf(a4.y, k4.y, s[1][1]);
      s[1][2] = fmaf(a4.y, k4.z, s[1][2]); s[1][3] = fmaf(a4.y, k4.w, s[1][3]);
      s[2][0] = fmaf(a4.z, k4.x, s[2][0]); s[2][1] = fmaf(a4.z, k4.y, s[2][1]);
      s[2][2] = fmaf(a4.z, k4.z, s[2][2]); s[2][3] = fmaf(a4.z, k4.w, s[2][3]);
      s[3][0] = fmaf(a4.w, k4.x, s[3][0]); s[3][1] = fmaf(a4.w, k4.y, s[3][1]);
      s[3][2] = fmaf(a4.w, k4.z, s[3][2]); s[3][3] = fmaf(a4.w, k4.w, s[3][3]);
    }
#pragma unroll
    for (int i = 0; i < 4; ++i) {
      int a = ty * 4 + i;
      int ac = a < AG ? a : AG - 1;             // clamp (padded rows: values unused)
      float4 p4 = *(const float4*)(pbh + (size_t)ac * NTOK + n0 + tx * 4);
      float e0 = __expf(s[i][0] + p4.x);
      float e1 = __expf(s[i][1] + p4.y);
      float e2 = __expf(s[i][2] + p4.z);
      float e3 = __expf(s[i][3] + p4.w);
      lR[i] += e0 + e1 + e2 + e3;
      eT[tx * 4 + 0][a] = e0; eT[tx * 4 + 1][a] = e1;
      eT[tx * 4 + 2][a] = e2; eT[tx * 4 + 3][a] = e3;
    }
    __syncthreads();
#pragma unroll 4
    for (int n = 0; n < 64; ++n) {
      float4 e4 = *(float4*)&eT[n][ty * 4];
      float4 v4 = *(float4*)&vt[n][tx * 4];
      accR[0][0] = fmaf(e4.x, v4.x, accR[0][0]); accR[0][1] = fmaf(e4.x, v4.y, accR[0][1]);
      accR[0][2] = fmaf(e4.x, v4.z, accR[0][2]); accR[0][3] = fmaf(e4.x, v4.w, accR[0][3]);
      accR[1][0] = fmaf(e4.y, v4.x, accR[1][0]); accR[1][1] = fmaf(e4.y, v4.y, accR[1][1]);
      accR[1][2] = fmaf(e4.y, v4.z, accR[1][2]); accR[1][3] = fmaf(e4.y, v4.w, accR[1][3]);
      accR[2][0] = fmaf(e4.z, v4.x, accR[2][0]); accR[2][1] = fmaf(e4.z, v4.y, accR[2][1]);
      accR[2][2] = fmaf(e4.z, v4.z, accR[2][2]); accR[2][3] = fmaf(e4.z, v4.w, accR[2][3]);
      accR[3][0] = fmaf(e4.w, v4.x, accR[3][0]); accR[3][1] = fmaf(e4.w, v4.y, accR[3][1]);
      accR[3][2] = fmaf(e4.w, v4.z, accR[3][2]); accR[3][3] = fmaf(e4.w, v4.w, accR[3][3]);
    }
    __syncthreads();
  }
#pragma unroll
  for (int i = 0; i < 4; ++i) {
    float l = lR[i];
    l += __shfl_xor(l, 1, 64); l += __shfl_xor(l, 2, 64);
    l += __shfl_xor(l, 4, 64); l += __shfl_xor(l, 8, 64);
    lR[i] = l;
  }
  float* pn = part_num + ((size_t)(split * 128 + bh)) * 64 * 64;
  float* pl = part_l + (size_t)(split * 128 + bh) * 64;
#pragma unroll
  for (int i = 0; i < 4; ++i) {
    int a = ty * 4 + i;
    if (a < AG) {
      float4 o = {accR[i][0], accR[i][1], accR[i][2], accR[i][3]};
      *(float4*)(pn + a * 64 + tx * 4) = o;
      if (tx == 0) pl[a] = lR[i];
    }
  }
}

__global__ void agent_attn_combine(const float* __restrict__ part_num,
                                   const float* __restrict__ part_l,
                                   float* __restrict__ agent_v) {
  int idx = blockIdx.x * 256 + threadIdx.x;   // 128*49*64
  if (idx >= 128 * AG * 64) return;
  int d = idx & 63;
  int a = (idx >> 6) % AG;
  int bh = idx / (AG * 64);
  float num = 0.f, l = 0.f;
#pragma unroll
  for (int s = 0; s < ASPLIT; ++s) {
    num += part_num[((size_t)(s * 128 + bh)) * 4096 + a * 64 + d];
    l += part_l[(size_t)(s * 128 + bh) * 64 + a];
  }
  agent_v[((size_t)bh * AG + a) * HD + d] = num / l;
}

// ---------------- q attention fused: softmax_a(q*scale . agent^T + ab) @ agent_v ----------------
__global__ __launch_bounds__(256) void q_attn_kernel(const float* __restrict__ agent,
                                                     const float* __restrict__ agent_v,
                                                     const float* __restrict__ ab,
                                                     float* __restrict__ q) {
  const int tile = blockIdx.x;   // 16 tiles of 256 tokens
  const int h = blockIdx.y, b = blockIdx.z;
  __shared__ float ag[AG][HD];
  __shared__ float av[AG][HD];
  const int tid = threadIdx.x;
  const size_t base = ((size_t)(b * HEADS + h)) * AG * HD;
  for (int t = tid; t < AG * HD; t += 256) {
    ag[t / HD][t % HD] = agent[base + t] * 0.125f;
    av[t / HD][t % HD] = agent_v[base + t];
  }
  __syncthreads();
  const int nn = tile * 256 + tid;
  float* qrow = q + ((size_t)(b * NTOK) + nn) * INNER + h * 64;
  float qr[64];
#pragma unroll
  for (int d = 0; d < 64; d += 4) {
    float4 v4 = *(const float4*)(qrow + d);
    qr[d] = v4.x; qr[d + 1] = v4.y; qr[d + 2] = v4.z; qr[d + 3] = v4.w;
  }
  const float* abr = ab + ((size_t)h * NTOK + nn) * AG;
  float scr[AG];
  float m = -3.4e38f;
  for (int a = 0; a < AG; ++a) {
    float dot = 0.f;
#pragma unroll
    for (int d = 0; d < 64; ++d) dot = fmaf(qr[d], ag[a][d], dot);
    float s = dot + abr[a];
    scr[a] = s;
    m = fmaxf(m, s);
  }
  float l = 0.f;
  for (int a = 0; a < AG; ++a) {
    float e = __expf(scr[a] - m);
    scr[a] = e;
    l += e;
  }
  const float invl = 1.f / l;
#pragma unroll
  for (int d = 0; d < 64; ++d) qr[d] = 0.f;
  for (int a = 0; a < AG; ++a) {
    float p = scr[a] * invl;
#pragma unroll
    for (int d = 0; d < 64; ++d) qr[d] = fmaf(p, av[a][d], qr[d]);
  }
#pragma unroll
  for (int d = 0; d < 64; d += 4) {
    float4 v4 = {qr[d], qr[d + 1], qr[d + 2], qr[d + 3]};
    *(float4*)(qrow + d) = v4;
  }
}

// ---------------- depthwise 3x3 conv on v, added into out_pre ----------------
__global__ void dwc_kernel(const float* __restrict__ kv, const float* __restrict__ dwc_w,
                           const float* __restrict__ dwc_b, float* __restrict__ outp) {
  size_t idx = (size_t)blockIdx.x * 256 + threadIdx.x;   // 16*4096*512
  int c = (int)(idx & 511);
  size_t r = idx >> 9;
  int x = (int)(r & 63);
  int y = (int)((r >> 6) & 63);
  int b = (int)(r >> 12);
  const float* vb = kv + (size_t)b * NTOK * 1024 + 512 + c;
  float s = dwc_b[c];
#pragma unroll
  for (int ky = 0; ky < 3; ++ky) {
    int yy = y + ky - 1;
    if (yy < 0 || yy > 63) continue;
#pragma unroll
    for (int kx = 0; kx < 3; ++kx) {
      int xx = x + kx - 1;
      if (xx < 0 || xx > 63) continue;
      s = fmaf(dwc_w[c * 9 + ky * 3 + kx], vb[(size_t)(yy * 64 + xx) * 1024], s);
    }
  }
  outp[idx] += s;
}

// ---------------- host launcher ----------------
extern "C" void kernel_launch(void* const* d_in, const int* in_sizes, int n_in,
                              void* d_out, int out_size, void* d_ws, size_t ws_size,
                              hipStream_t stream) {
  const float* x       = (const float*)d_in[0];
  const float* context = (const float*)d_in[1];
  const float* q_w     = (const float*)d_in[2];
  const float* kv_w    = (const float*)d_in[3];
  const float* proj_w  = (const float*)d_in[4];
  const float* proj_b  = (const float*)d_in[5];
  const float* conv_w  = (const float*)d_in[6];
  const float* conv_b  = (const float*)d_in[7];
  const float* dwc_w   = (const float*)d_in[8];
  const float* dwc_b   = (const float*)d_in[9];
  const float* an_bias = (const float*)d_in[10];
  const float* na_bias = (const float*)d_in[11];
  const float* ah_bias = (const float*)d_in[12];
  const float* aw_bias = (const float*)d_in[13];
  const float* ha_bias = (const float*)d_in[14];
  const float* wa_bias = (const float*)d_in[15];
  float* out = (float*)d_out;
  float* wsf = (float*)d_ws;

  float* q_buf  = wsf + Q_OFF;    // later becomes out_pre
  float* kv_buf = wsf + KV_OFF;
  float* A2     = wsf + A2_OFF;
  float* Col    = wsf + COL_OFF;
  float* Cg     = wsf + CG_OFF;
  float* agent  = wsf + AGT_OFF;
  float* agentv = wsf + AGV_OFF;
  float* pb     = wsf + PB_OFF;
  float* ab     = wsf + AB_OFF;
  float* pnum   = wsf + PNUM_OFF;  // overlays Col (retired by then)
  float* pl     = wsf + PL_OFF;

  const int M = BB * NTOK;   // 65536

  // 1. q = x @ q_w^T
  gemm128<false><<<dim3(INNER / 128, M / 128), 256, 0, stream>>>(x, q_w, nullptr, q_buf, M, INNER, DIMC);
  // 2. kv = x @ kv_w^T
  gemm128<false><<<dim3(2 * INNER / 128, M / 128), 256, 0, stream>>>(x, kv_w, nullptr, kv_buf, M, 2 * INNER, DIMC);
  // 3. pooled concat
  pool_kernel<<<dim3(AG, BB), 256, 0, stream>>>(q_buf, context, A2);
  // 4. im2col
  im2col_kernel<<<(784 * 6912 + 255) / 256, 256, 0, stream>>>(A2, Col);
  // 5. conv as GEMM, split-K with atomics (zero Cg first)
  zero_kernel<<<(784 * INNER + 255) / 256, 256, 0, stream>>>(Cg, 784 * INNER);
  conv_gemm_splitk<<<dim3(INNER / 64, (784 + 63) / 64, CKS), 256, 0, stream>>>(Col, conv_w, Cg);
  // 6. scramble + conv bias -> agent[b,h,a,d]
  agent_scatter_kernel<<<(BB * HEADS * AG * HD + 255) / 256, 256, 0, stream>>>(Cg, conv_b, agent);
  // 7./8. bias tables
  pb_kernel<<<(HEADS * AG * NTOK + 255) / 256, 256, 0, stream>>>(an_bias, ah_bias, aw_bias, pb);
  ab_kernel<<<(HEADS * NTOK * AG + 255) / 256, 256, 0, stream>>>(na_bias, ha_bias, wa_bias, ab);
  // 9. agent attention -> partials -> agent_v   (Col region retired, reused for partials)
  agent_attn_s<<<dim3(ASPLIT, HEADS, BB), 256, 0, stream>>>(kv_buf, agent, pb, pnum, pl);
  agent_attn_combine<<<(128 * AG * 64 + 255) / 256, 256, 0, stream>>>(pnum, pl, agentv);
  // 10. q attention (q_buf overwritten with out_pre)
  q_attn_kernel<<<dim3(NTOK / 256, HEADS, BB), 256, 0, stream>>>(agent, agentv, ab, q_buf);
  // 11. depthwise conv on v added into out_pre
  dwc_kernel<<<(BB * NTOK * INNER) / 256, 256, 0, stream>>>(kv_buf, dwc_w, dwc_b, q_buf);
  // 12. final projection with bias
  gemm128<true><<<dim3(DIMC / 128, M / 128), 256, 0, stream>>>(q_buf, proj_w, proj_b, out, M, DIMC, INNER);

  (void)in_sizes; (void)n_in; (void)out_size; (void)ws_size;
}